// Round 1
// baseline (1359.402 us; speedup 1.0000x reference)
//
#include <hip/hip_runtime.h>

#define Bsz 1024
#define Tt 200
#define Hh 128
#define Gg 384
#define OUT0_SZ (1024L*199*128)

#define WSEG 49152              // frag elements per gate matrix (384*128)
#define WTOT (4*WSEG + 16384)   // + h2o (128*128)

typedef _Float16 half8 __attribute__((ext_vector_type(8)));
typedef float floatx4 __attribute__((ext_vector_type(4)));

// LDS-only barrier: do NOT drain vmcnt -> weight/emb prefetch and output
// stores stay in flight across phases (the old __syncthreads drained
// vmcnt(0) six times per step, serializing all global traffic).
#define BAR() asm volatile("s_waitcnt lgkmcnt(0)\n\ts_barrier" ::: "memory")

__device__ __forceinline__ float fsigm(float x) {
    return __builtin_amdgcn_rcpf(1.f + __expf(-x));
}
__device__ __forceinline__ float ftanh(float x) {
    float e = __expf(2.f * x);              // inf-safe: e=inf -> 1, e=0 -> -1
    return 1.f - 2.f * __builtin_amdgcn_rcpf(e + 1.f);
}

// Pack fp32 weights into fp16 MFMA B-fragment order:
// idx = ((tile*4 + kstep)*64 + lane)*8 + j  ->  W[tile*16 + (lane&15)][kstep*32 + (lane>>4)*8 + j]
__global__ void pack_weights(const float* __restrict__ Wih, const float* __restrict__ Whh,
                             const float* __restrict__ h2o_w, ushort* __restrict__ wbuf) {
    int idx = blockIdx.x * blockDim.x + threadIdx.x;
    if (idx >= WTOT) return;
    const float* src; int off;
    if      (idx <   WSEG) { src = Wih;            off = idx;          }
    else if (idx < 2*WSEG) { src = Whh;            off = idx -   WSEG; }
    else if (idx < 3*WSEG) { src = Wih + Gg*Hh;    off = idx - 2*WSEG; }
    else if (idx < 4*WSEG) { src = Whh + Gg*Hh;    off = idx - 3*WSEG; }
    else                   { src = h2o_w;          off = idx - 4*WSEG; }
    int j    = off & 7;
    int lane = (off >> 3) & 63;
    int kt   = (off >> 9) & 3;
    int tile = off >> 11;
    int n = tile*16 + (lane & 15);
    int k = kt*32 + (lane >> 4)*8 + j;
    union { _Float16 h; ushort u; } cv;
    cv.h = (_Float16)src[n*Hh + k];
    wbuf[idx] = cv.u;
}

// blocks 0..63: GRU over 16 batch rows each, all 200 steps.
// blocks 64..255: gather/copy of out1, out2, out3-first-half.
__global__ __launch_bounds__(512) void gru_fused(
    const int* __restrict__ il, const float* __restrict__ mask,
    const int* __restrict__ negl, const float* __restrict__ emb,
    const float* __restrict__ bih, const float* __restrict__ bhh,
    const float* __restrict__ h2o_b, const ushort* __restrict__ wbuf,
    float* __restrict__ out)
{
    __shared__ _Float16 xa_lds[2][16*136]; // dbuf: emb x_t at step start, h2o input mid-step
    __shared__ _Float16 x1_lds[16*136];    // layer1 input (h0 pre-mask)
    __shared__ _Float16 h0_lds[16*136];    // masked state L0
    __shared__ _Float16 h1_lds[16*136];    // masked state L1
    __shared__ float    g_lds[16*516];     // gates: [b][n] n<128:r 128..255:z 256..383:inn 384..511:hn
    __shared__ float    brz_s[2*256];      // bih+bhh for r,z per layer
    __shared__ float    bin_s[2*128];
    __shared__ float    bhn_s[2*128];
    __shared__ float    bo_s[128];
    __shared__ int      il_s[16*Tt];       // per-block interaction ids, all steps
    __shared__ float    keep_f[16*Tt];     // per-block keep mask, all steps

    const int tid = threadIdx.x;
    float* out0 = out;
    float* out1 = out + OUT0_SZ;
    float* out2 = out + 2*OUT0_SZ;
    float* out3 = out + 3*OUT0_SZ;

    if (blockIdx.x >= 64) {
        // ---------------- copy path ----------------
        const float4* emb4 = (const float4*)emb;
        float4* o1 = (float4*)out1;
        float4* o2 = (float4*)out2;
        float4* o3 = (float4*)out3;
        const int nA = 1024*200*32;      // out3 first half, float4 tasks
        const int nB = 1024*199*32;      // out1 / out2
        const int total = nA + 2*nB;
        const int stride = 192*512;
        for (int i = (blockIdx.x - 64)*512 + tid; i < total; i += stride) {
            if (i < nA) {
                int c = i & 31; int bt = i >> 5;
                int e = il[bt];
                o3[bt*64 + c] = emb4[(long)e*32 + c];           // row=256 floats, first half
            } else if (i < nA + nB) {
                int ii = i - nA; int c = ii & 31; int bt = ii >> 5;
                int b = bt / 199, t = bt - b*199;
                int e = il[b*Tt + t + 1];
                o1[bt*32 + c] = emb4[(long)e*32 + c];
            } else {
                int ii = i - nA - nB; int c = ii & 31; int bt = ii >> 5;
                int b = bt / 199, t = bt - b*199;
                int e = negl[b*Tt + t];
                o2[bt*32 + c] = emb4[(long)e*32 + c];
            }
        }
        return;
    }

    // ---------------- GRU path ----------------
    const int wave = tid >> 6;
    const int lane = tid & 63;
    const int b0   = blockIdx.x * 16;
    const int col  = lane & 15;
    const int q    = lane >> 4;
    const int arow = (lane & 15)*136;    // A-frag row base
    const int koffq = (lane >> 4)*8;

    // biases -> LDS (r,z combined; n-gate kept separate)
    { int l = tid >> 8, n = tid & 255; brz_s[tid] = bih[l*Gg + n] + bhh[l*Gg + n]; }
    if (tid < 256) { int l = tid >> 7, jj = tid & 127; bin_s[tid] = bih[l*Gg + 256 + jj]; bhn_s[tid] = bhh[l*Gg + 256 + jj]; }
    if (tid < 128) bo_s[tid] = h2o_b[tid];
    for (int i = tid; i < 16*136; i += 512) { h0_lds[i] = (_Float16)0.f; h1_lds[i] = (_Float16)0.f; }
    // hoist il/mask for all 200 steps into LDS (removes il->emb dependent
    // chain from the loop; mask converted to keep once)
    for (int i = tid; i < 16*Tt; i += 512) {
        int r = i / Tt, c = i - r*Tt;
        il_s[i]   = il[(b0 + r)*Tt + c];
        keep_f[i] = (mask[(b0 + r)*Tt + c] != 0.f) ? 1.f : 0.f;
    }

    // persistent register weights: layer0 (wave w owns gate tiles w, 8+w, 16+w)
    const half8* wb = (const half8*)wbuf;
    half8 wih0[3][4], whh0[3][4];
#pragma unroll
    for (int s = 0; s < 3; s++) {
        const int tl = (s == 0) ? wave : (s == 1) ? (8 + wave) : (16 + wave);
#pragma unroll
        for (int k = 0; k < 4; k++) {
            wih0[s][k] = wb[0*6144 + (tl*4 + k)*64 + lane];
            whh0[s][k] = wb[1*6144 + (tl*4 + k)*64 + lane];
        }
    }

    // prologue: gather emb for t=0 into xa[0]
    {
        int r = tid >> 5, c4 = tid & 31;
        int e = il[(b0 + r)*Tt];
        float4 v = ((const float4*)emb)[(long)e*32 + c4];
        _Float16* dst = &xa_lds[0][r*136 + c4*4];
        dst[0] = (_Float16)v.x; dst[1] = (_Float16)v.y;
        dst[2] = (_Float16)v.z; dst[3] = (_Float16)v.w;
    }
    __syncthreads();   // one full barrier (drains prologue), then raw barriers only

    const int r5 = tid >> 5, c4g = tid & 31;

    for (int t = 0; t < Tt; t++) {
        _Float16* cur = xa_lds[t & 1];
        _Float16* nxt = xa_lds[(t + 1) & 1];

        // ---- issue emb gather for t+1 (regs); landed into nxt during L1 elem ----
        float4 pv;
        if (t < Tt - 1) {
            int e = il_s[r5*Tt + t + 1];
            pv = ((const float4*)emb)[(long)e*32 + c4g];
        }

        half8 p_w1r[4], p_w1z[4], p_w1n[4], p_whr[4], p_whz[4], p_whn[4];
        // ---- L0 MFMA ----
        {
            floatx4 acc_r = {0.f,0.f,0.f,0.f}, acc_z = {0.f,0.f,0.f,0.f};
            floatx4 acc_in = {0.f,0.f,0.f,0.f}, acc_hn = {0.f,0.f,0.f,0.f};
#pragma unroll
            for (int k = 0; k < 4; k++) {
                half8 xf = *(const half8*)&cur[arow + k*32 + koffq];
                half8 hf = *(const half8*)&h0_lds[arow + k*32 + koffq];
                acc_r  = __builtin_amdgcn_mfma_f32_16x16x32_f16(xf, wih0[0][k], acc_r, 0, 0, 0);
                acc_r  = __builtin_amdgcn_mfma_f32_16x16x32_f16(hf, whh0[0][k], acc_r, 0, 0, 0);
                acc_z  = __builtin_amdgcn_mfma_f32_16x16x32_f16(xf, wih0[1][k], acc_z, 0, 0, 0);
                acc_z  = __builtin_amdgcn_mfma_f32_16x16x32_f16(hf, whh0[1][k], acc_z, 0, 0, 0);
                acc_in = __builtin_amdgcn_mfma_f32_16x16x32_f16(xf, wih0[2][k], acc_in, 0, 0, 0);
                acc_hn = __builtin_amdgcn_mfma_f32_16x16x32_f16(hf, whh0[2][k], acc_hn, 0, 0, 0);
            }
#pragma unroll
            for (int r2 = 0; r2 < 4; r2++) {
                int row = q*4 + r2;
                g_lds[row*516 +       wave*16 + col] = acc_r[r2];
                g_lds[row*516 + 128 + wave*16 + col] = acc_z[r2];
                g_lds[row*516 + 256 + wave*16 + col] = acc_in[r2];
                g_lds[row*516 + 384 + wave*16 + col] = acc_hn[r2];
            }
            // prefetch layer1 weight fragments from L2 — now genuinely stays
            // in flight across the lgkm-only barriers until the L1 MFMA uses it
#pragma unroll
            for (int k = 0; k < 4; k++) {
                p_w1r[k] = wb[2*6144 + (( 0 + wave)*4 + k)*64 + lane];
                p_w1z[k] = wb[2*6144 + (( 8 + wave)*4 + k)*64 + lane];
                p_w1n[k] = wb[2*6144 + ((16 + wave)*4 + k)*64 + lane];
                p_whr[k] = wb[3*6144 + (( 0 + wave)*4 + k)*64 + lane];
                p_whz[k] = wb[3*6144 + (( 8 + wave)*4 + k)*64 + lane];
                p_whn[k] = wb[3*6144 + ((16 + wave)*4 + k)*64 + lane];
            }
        }
        BAR();

        // ---- L0 elementwise: gates -> h0new; x1_lds=pre-mask, h0_lds=masked ----
        {
            int jj = tid & 127, bq = tid >> 7;
#pragma unroll
            for (int itr = 0; itr < 4; itr++) {
                int b = itr*4 + bq;
                float gr  = g_lds[b*516 +       jj] + brz_s[jj];
                float gz  = g_lds[b*516 + 128 + jj] + brz_s[128 + jj];
                float gin = g_lds[b*516 + 256 + jj] + bin_s[jj];
                float ghn = g_lds[b*516 + 384 + jj] + bhn_s[jj];
                float rr = fsigm(gr);
                float zz = fsigm(gz);
                float nn = ftanh(gin + rr*ghn);
                float hp = (float)h0_lds[b*136 + jj];
                float hv = (1.f - zz)*nn + zz*hp;
                x1_lds[b*136 + jj] = (_Float16)hv;
                h0_lds[b*136 + jj] = (_Float16)(hv * keep_f[b*Tt + t]);
            }
        }
        BAR();

        half8 p_o[4];
        // ---- L1 MFMA (streamed weights) ----
        {
            floatx4 acc_r = {0.f,0.f,0.f,0.f}, acc_z = {0.f,0.f,0.f,0.f};
            floatx4 acc_in = {0.f,0.f,0.f,0.f}, acc_hn = {0.f,0.f,0.f,0.f};
#pragma unroll
            for (int k = 0; k < 4; k++) {
                half8 xf = *(const half8*)&x1_lds[arow + k*32 + koffq];
                half8 hf = *(const half8*)&h1_lds[arow + k*32 + koffq];
                acc_r  = __builtin_amdgcn_mfma_f32_16x16x32_f16(xf, p_w1r[k], acc_r, 0, 0, 0);
                acc_r  = __builtin_amdgcn_mfma_f32_16x16x32_f16(hf, p_whr[k], acc_r, 0, 0, 0);
                acc_z  = __builtin_amdgcn_mfma_f32_16x16x32_f16(xf, p_w1z[k], acc_z, 0, 0, 0);
                acc_z  = __builtin_amdgcn_mfma_f32_16x16x32_f16(hf, p_whz[k], acc_z, 0, 0, 0);
                acc_in = __builtin_amdgcn_mfma_f32_16x16x32_f16(xf, p_w1n[k], acc_in, 0, 0, 0);
                acc_hn = __builtin_amdgcn_mfma_f32_16x16x32_f16(hf, p_whn[k], acc_hn, 0, 0, 0);
            }
#pragma unroll
            for (int r2 = 0; r2 < 4; r2++) {
                int row = q*4 + r2;
                g_lds[row*516 +       wave*16 + col] = acc_r[r2];
                g_lds[row*516 + 128 + wave*16 + col] = acc_z[r2];
                g_lds[row*516 + 256 + wave*16 + col] = acc_in[r2];
                g_lds[row*516 + 384 + wave*16 + col] = acc_hn[r2];
            }
            // prefetch h2o fragments
#pragma unroll
            for (int k = 0; k < 4; k++) p_o[k] = wb[4*6144 + (wave*4 + k)*64 + lane];
        }
        BAR();

        // ---- L1 elementwise: h1new; cur=pre-mask (h2o input), h1_lds=masked;
        //      also land the prefetched emb for t+1 into nxt ----
        {
            int jj = tid & 127, bq = tid >> 7;
#pragma unroll
            for (int itr = 0; itr < 4; itr++) {
                int b = itr*4 + bq;
                float gr  = g_lds[b*516 +       jj] + brz_s[256 + jj];
                float gz  = g_lds[b*516 + 128 + jj] + brz_s[256 + 128 + jj];
                float gin = g_lds[b*516 + 256 + jj] + bin_s[128 + jj];
                float ghn = g_lds[b*516 + 384 + jj] + bhn_s[128 + jj];
                float rr = fsigm(gr);
                float zz = fsigm(gz);
                float nn = ftanh(gin + rr*ghn);
                float hp = (float)h1_lds[b*136 + jj];
                float hv = (1.f - zz)*nn + zz*hp;
                cur[b*136 + jj]    = (_Float16)hv;
                h1_lds[b*136 + jj] = (_Float16)(hv * keep_f[b*Tt + t]);
            }
            if (t < Tt - 1) {
                _Float16* dst = &nxt[r5*136 + c4g*4];
                dst[0] = (_Float16)pv.x; dst[1] = (_Float16)pv.y;
                dst[2] = (_Float16)pv.z; dst[3] = (_Float16)pv.w;
            }
        }
        BAR();

        // ---- h2o: out = tanh(h1new @ h2o_w^T + b); write out3 (and out0 for t<199) ----
        // no trailing barrier: next step's first LDS writes (g_lds) are only
        // reached after all waves pass this step's B4, and xa WAR is 3 barriers away.
        {
            floatx4 acc_o = {0.f,0.f,0.f,0.f};
#pragma unroll
            for (int k = 0; k < 4; k++) {
                half8 xf = *(const half8*)&cur[arow + k*32 + koffq];
                acc_o = __builtin_amdgcn_mfma_f32_16x16x32_f16(xf, p_o[k], acc_o, 0, 0, 0);
            }
            int nout = wave*16 + col;
            float bs = bo_s[nout];
#pragma unroll
            for (int r2 = 0; r2 < 4; r2++) {
                int brow = q*4 + r2;
                float v = ftanh(acc_o[r2] + bs);
                out3[((long)(b0 + brow)*Tt + t)*256 + 128 + nout] = v;
                if (t < Tt - 1) out0[((long)(b0 + brow)*199 + t)*128 + nout] = v;
            }
        }
    }
}

extern "C" void kernel_launch(void* const* d_in, const int* in_sizes, int n_in,
                              void* d_out, int out_size, void* d_ws, size_t ws_size,
                              hipStream_t stream) {
    const int*   il    = (const int*)  d_in[0];
    const float* msk   = (const float*)d_in[1];
    const int*   negl  = (const int*)  d_in[2];
    const float* emb   = (const float*)d_in[3];
    const float* Wih   = (const float*)d_in[4];
    const float* Whh   = (const float*)d_in[5];
    const float* bih   = (const float*)d_in[6];
    const float* bhh   = (const float*)d_in[7];
    const float* h2o_w = (const float*)d_in[8];
    const float* h2o_b = (const float*)d_in[9];
    float* out = (float*)d_out;
    ushort* wbuf = (ushort*)d_ws;

    pack_weights<<<(WTOT + 255)/256, 256, 0, stream>>>(Wih, Whh, h2o_w, wbuf);
    gru_fused<<<256, 512, 0, stream>>>(il, msk, negl, emb, bih, bhh, h2o_b, wbuf, out);
}

// Round 2
// 1147.159 us; speedup vs baseline: 1.1850x; 1.1850x over previous
//
#include <hip/hip_runtime.h>

#define Bsz 1024
#define Tt 200
#define Hh 128
#define Gg 384
#define OUT0_SZ (1024L*199*128)

#define WSEG 49152              // frag elements per gate matrix (384*128)
#define WTOT (4*WSEG + 16384)   // + h2o (128*128)

typedef _Float16 half8 __attribute__((ext_vector_type(8)));
typedef float floatx4 __attribute__((ext_vector_type(4)));

// LDS-only barrier: do NOT drain vmcnt -> weight/emb prefetch and output
// stores stay in flight across phases.
#define BAR() asm volatile("s_waitcnt lgkmcnt(0)\n\ts_barrier" ::: "memory")

#define MFMA16(A, B, C) __builtin_amdgcn_mfma_f32_16x16x32_f16((A), (B), (C), 0, 0, 0)

__device__ __forceinline__ float fsigm(float x) {
    return __builtin_amdgcn_rcpf(1.f + __expf(-x));
}
__device__ __forceinline__ float ftanh(float x) {
    float e = __expf(2.f * x);              // inf-safe: e=inf -> 1, e=0 -> -1
    return 1.f - 2.f * __builtin_amdgcn_rcpf(e + 1.f);
}

// Pack fp32 weights into fp16 MFMA B-fragment order:
// idx = ((tile*4 + kstep)*64 + lane)*8 + j  ->  W[tile*16 + (lane&15)][kstep*32 + (lane>>4)*8 + j]
__global__ void pack_weights(const float* __restrict__ Wih, const float* __restrict__ Whh,
                             const float* __restrict__ h2o_w, ushort* __restrict__ wbuf) {
    int idx = blockIdx.x * blockDim.x + threadIdx.x;
    if (idx >= WTOT) return;
    const float* src; int off;
    if      (idx <   WSEG) { src = Wih;            off = idx;          }
    else if (idx < 2*WSEG) { src = Whh;            off = idx -   WSEG; }
    else if (idx < 3*WSEG) { src = Wih + Gg*Hh;    off = idx - 2*WSEG; }
    else if (idx < 4*WSEG) { src = Whh + Gg*Hh;    off = idx - 3*WSEG; }
    else                   { src = h2o_w;          off = idx - 4*WSEG; }
    int j    = off & 7;
    int lane = (off >> 3) & 63;
    int kt   = (off >> 9) & 3;
    int tile = off >> 11;
    int n = tile*16 + (lane & 15);
    int k = kt*32 + (lane >> 4)*8 + j;
    union { _Float16 h; ushort u; } cv;
    cv.h = (_Float16)src[n*Hh + k];
    wbuf[idx] = cv.u;
}

// blocks 0..63: GRU over 16 batch rows each, all 200 steps.
// blocks 64..255: gather/copy of out1, out2, out3-first-half.
//
// Per step, TWO phases / TWO barriers:
//  phaseA: L0 MFMA (x from xa[t&1], h from h0[t&1]) + in-register elementwise
//          (gate cols owned by the computing wave) -> x1_lds + h0[(t+1)&1];
//          also h2o MFMA for step t-1 (reads xa[(t+1)&1] = h1pre(t-1)) + stores.
//  phaseB: L1 MFMA (x1, h1[t&1]) + in-register elementwise -> xa[t&1] (=h2o
//          input for next phaseA) + h1[(t+1)&1]; land prefetched emb(t+1)
//          into xa[(t+1)&1]; issue emb(t+2) gather.
// Hidden-state buffers are MFMA-fragment-linear: half8 index = k*64 + lane,
// so A-frag ds_read_b128 is conflict-free; h-state double-buffered to avoid
// intra-phase WAR (writers vs other waves' readers).
__global__ __launch_bounds__(512, 2) void gru_fused(
    const int* __restrict__ il, const float* __restrict__ mask,
    const int* __restrict__ negl, const float* __restrict__ emb,
    const float* __restrict__ bih, const float* __restrict__ bhh,
    const float* __restrict__ h2o_b, const ushort* __restrict__ wbuf,
    float* __restrict__ out)
{
    __shared__ half8 xa_f[2][256];   // emb-x / h1pre, frag-linear, dbuf
    __shared__ half8 x1_f[256];      // L1 input (h0 pre-mask)
    __shared__ half8 h0_f[2][256];   // masked state L0, dbuf
    __shared__ half8 h1_f[2][256];   // masked state L1, dbuf
    __shared__ int   il_s[16*Tt];
    __shared__ float keep_s[16*Tt];

    const int tid = threadIdx.x;
    float* out0 = out;
    float* out1 = out + OUT0_SZ;
    float* out2 = out + 2*OUT0_SZ;
    float* out3 = out + 3*OUT0_SZ;

    if (blockIdx.x >= 64) {
        // ---------------- copy path ----------------
        const float4* emb4 = (const float4*)emb;
        float4* o1 = (float4*)out1;
        float4* o2 = (float4*)out2;
        float4* o3 = (float4*)out3;
        const int nA = 1024*200*32;      // out3 first half, float4 tasks
        const int nB = 1024*199*32;      // out1 / out2
        const int total = nA + 2*nB;
        const int stride = 192*512;
        for (int i = (blockIdx.x - 64)*512 + tid; i < total; i += stride) {
            if (i < nA) {
                int c = i & 31; int bt = i >> 5;
                int e = il[bt];
                o3[bt*64 + c] = emb4[(long)e*32 + c];
            } else if (i < nA + nB) {
                int ii = i - nA; int c = ii & 31; int bt = ii >> 5;
                int b = bt / 199, t = bt - b*199;
                int e = il[b*Tt + t + 1];
                o1[bt*32 + c] = emb4[(long)e*32 + c];
            } else {
                int ii = i - nA - nB; int c = ii & 31; int bt = ii >> 5;
                int b = bt / 199, t = bt - b*199;
                int e = negl[b*Tt + t];
                o2[bt*32 + c] = emb4[(long)e*32 + c];
            }
        }
        return;
    }

    // ---------------- GRU path ----------------
    const int wave = tid >> 6;
    const int lane = tid & 63;
    const int b0   = blockIdx.x * 16;
    const int cl   = lane & 15;          // acc col within wave tile
    const int q    = lane >> 4;          // acc row group (rows q*4..q*4+3)
    const int col  = wave*16 + cl;       // global hidden/output column owned

    // frag-linear write index for element (row = q*4+r2, hidden col = col):
    // halfidx = ((ktile*64 + q'*16 + row)*8 + j), ktile=wave>>1,
    // q' = (wave&1)*2 + (cl>>3), j = cl&7
    const int hidx0 = ((wave >> 1)*64 + ((wave & 1)*2 + (cl >> 3))*16 + q*4)*8 + (cl & 7);

    // emb gather mapping: thread handles batch-row r5, float4 chunk c4
    const int r5 = tid >> 5, c4 = tid & 31;
    const int ebase = ((c4 >> 3)*64 + ((c4 & 7) >> 1)*16 + r5)*8 + (c4 & 1)*4;

    // il/keep for all steps -> LDS; zero h-state
    for (int i = tid; i < 16*Tt; i += 512) {
        int r = i / Tt, c = i - r*Tt;
        il_s[i]   = il[(b0 + r)*Tt + c];
        keep_s[i] = (mask[(b0 + r)*Tt + c] != 0.f) ? 1.f : 0.f;
    }
    {
        _Float16* z0 = (_Float16*)h0_f;
        _Float16* z1 = (_Float16*)h1_f;
        for (int i = tid; i < 4096; i += 512) { z0[i] = (_Float16)0.f; z1[i] = (_Float16)0.f; }
    }

    // per-lane biases (column-fixed for the whole kernel)
    const float br0 = bih[col]       + bhh[col];
    const float bz0 = bih[128 + col] + bhh[128 + col];
    const float bi0 = bih[256 + col];
    const float bh0 = bhh[256 + col];
    const float br1 = bih[384 + col]       + bhh[384 + col];
    const float bz1 = bih[384 + 128 + col] + bhh[384 + 128 + col];
    const float bi1 = bih[384 + 256 + col];
    const float bh1 = bhh[384 + 256 + col];
    const float bo  = h2o_b[col];

    // persistent register weights: L0 (wave w owns gate tiles w, 8+w, 16+w) + h2o
    const half8* wb = (const half8*)wbuf;
    half8 wih0[3][4], whh0[3][4], p_o[4];
#pragma unroll
    for (int s = 0; s < 3; s++) {
        const int tl = (s == 0) ? wave : (s == 1) ? (8 + wave) : (16 + wave);
#pragma unroll
        for (int k = 0; k < 4; k++) {
            wih0[s][k] = wb[0*6144 + (tl*4 + k)*64 + lane];
            whh0[s][k] = wb[1*6144 + (tl*4 + k)*64 + lane];
        }
    }
#pragma unroll
    for (int k = 0; k < 4; k++) p_o[k] = wb[4*6144 + (wave*4 + k)*64 + lane];

    const float4* emb4v = (const float4*)emb;
    // prologue: emb(0) -> xa[0]; issue emb(1) into pv
    {
        int e = il[(b0 + r5)*Tt];
        float4 v = emb4v[(long)e*32 + c4];
        _Float16* d = (_Float16*)xa_f[0];
        d[ebase]   = (_Float16)v.x; d[ebase+1] = (_Float16)v.y;
        d[ebase+2] = (_Float16)v.z; d[ebase+3] = (_Float16)v.w;
    }
    float4 pv;
    { int e = il[(b0 + r5)*Tt + 1]; pv = emb4v[(long)e*32 + c4]; }

    float hprev0[4] = {0.f,0.f,0.f,0.f};
    float hprev1[4] = {0.f,0.f,0.f,0.f};
    __syncthreads();

    for (int t = 0; t < Tt; t++) {
        float k4[4];
#pragma unroll
        for (int r2 = 0; r2 < 4; r2++) k4[r2] = keep_s[(q*4 + r2)*Tt + t];

        // ---------------- phase A ----------------
        const half8* xcur = xa_f[t & 1];
        const half8* hcur = h0_f[t & 1];
        floatx4 acc_r = {0,0,0,0}, acc_z = {0,0,0,0}, acc_in = {0,0,0,0}, acc_hn = {0,0,0,0};
#pragma unroll
        for (int k = 0; k < 4; k++) {
            half8 xf = xcur[k*64 + lane];
            half8 hf = hcur[k*64 + lane];
            acc_r  = MFMA16(xf, wih0[0][k], acc_r);
            acc_r  = MFMA16(hf, whh0[0][k], acc_r);
            acc_z  = MFMA16(xf, wih0[1][k], acc_z);
            acc_z  = MFMA16(hf, whh0[1][k], acc_z);
            acc_in = MFMA16(xf, wih0[2][k], acc_in);
            acc_hn = MFMA16(hf, whh0[2][k], acc_hn);
        }
        // deferred h2o for step t-1 (input = h1pre(t-1) in xa[(t+1)&1])
        floatx4 acc_o = {0,0,0,0};
        if (t > 0) {
            const half8* hx = xa_f[(t + 1) & 1];
#pragma unroll
            for (int k = 0; k < 4; k++) acc_o = MFMA16(hx[k*64 + lane], p_o[k], acc_o);
        }
        // prefetch L1 weights (L2-resident; used after the barrier)
        half8 p_w1r[4], p_w1z[4], p_w1n[4], p_whr[4], p_whz[4], p_whn[4];
#pragma unroll
        for (int k = 0; k < 4; k++) {
            p_w1r[k] = wb[2*6144 + (( 0 + wave)*4 + k)*64 + lane];
            p_w1z[k] = wb[2*6144 + (( 8 + wave)*4 + k)*64 + lane];
            p_w1n[k] = wb[2*6144 + ((16 + wave)*4 + k)*64 + lane];
            p_whr[k] = wb[3*6144 + (( 0 + wave)*4 + k)*64 + lane];
            p_whz[k] = wb[3*6144 + (( 8 + wave)*4 + k)*64 + lane];
            p_whn[k] = wb[3*6144 + ((16 + wave)*4 + k)*64 + lane];
        }
        // in-register L0 elementwise (wave owns gates r,z,n for its cols)
        {
            _Float16* x1h = (_Float16*)x1_f;
            _Float16* h0n = (_Float16*)h0_f[(t + 1) & 1];
#pragma unroll
            for (int r2 = 0; r2 < 4; r2++) {
                float gr = acc_r[r2]  + br0;
                float gz = acc_z[r2]  + bz0;
                float gn = acc_in[r2] + bi0;
                float gh = acc_hn[r2] + bh0;
                float rr = fsigm(gr);
                float zz = fsigm(gz);
                float nn = ftanh(gn + rr*gh);
                float hv = (1.f - zz)*nn + zz*hprev0[r2];
                x1h[hidx0 + r2*8] = (_Float16)hv;
                hprev0[r2] = hv * k4[r2];
                h0n[hidx0 + r2*8] = (_Float16)hprev0[r2];
            }
        }
        // h2o epilogue for t-1: tanh + global stores (never drained in-loop)
        if (t > 0) {
            int tt = t - 1;
#pragma unroll
            for (int r2 = 0; r2 < 4; r2++) {
                int brow = q*4 + r2;
                float v = ftanh(acc_o[r2] + bo);
                out3[((long)(b0 + brow)*Tt + tt)*256 + 128 + col] = v;
                out0[((long)(b0 + brow)*199 + tt)*128 + col] = v;
            }
        }
        BAR();

        // ---------------- phase B ----------------
        const half8* h1cur = h1_f[t & 1];
        floatx4 b_r = {0,0,0,0}, b_z = {0,0,0,0}, b_in = {0,0,0,0}, b_hn = {0,0,0,0};
#pragma unroll
        for (int k = 0; k < 4; k++) {
            half8 xf = x1_f[k*64 + lane];
            half8 hf = h1cur[k*64 + lane];
            b_r  = MFMA16(xf, p_w1r[k], b_r);
            b_r  = MFMA16(hf, p_whr[k], b_r);
            b_z  = MFMA16(xf, p_w1z[k], b_z);
            b_z  = MFMA16(hf, p_whz[k], b_z);
            b_in = MFMA16(xf, p_w1n[k], b_in);
            b_hn = MFMA16(hf, p_whn[k], b_hn);
        }
        // in-register L1 elementwise; h1pre -> xa[t&1] (h2o input next phaseA)
        {
            _Float16* xah = (_Float16*)xa_f[t & 1];
            _Float16* h1n = (_Float16*)h1_f[(t + 1) & 1];
#pragma unroll
            for (int r2 = 0; r2 < 4; r2++) {
                float gr = b_r[r2]  + br1;
                float gz = b_z[r2]  + bz1;
                float gn = b_in[r2] + bi1;
                float gh = b_hn[r2] + bh1;
                float rr = fsigm(gr);
                float zz = fsigm(gz);
                float nn = ftanh(gn + rr*gh);
                float hv = (1.f - zz)*nn + zz*hprev1[r2];
                xah[hidx0 + r2*8] = (_Float16)hv;
                hprev1[r2] = hv * k4[r2];
                h1n[hidx0 + r2*8] = (_Float16)hprev1[r2];
            }
        }
        // land prefetched emb(t+1) -> xa[(t+1)&1]; issue emb(t+2)
        if (t + 1 < Tt) {
            _Float16* d = (_Float16*)xa_f[(t + 1) & 1];
            d[ebase]   = (_Float16)pv.x; d[ebase+1] = (_Float16)pv.y;
            d[ebase+2] = (_Float16)pv.z; d[ebase+3] = (_Float16)pv.w;
        }
        if (t + 2 < Tt) {
            int e = il_s[r5*Tt + t + 2];
            pv = emb4v[(long)e*32 + c4];
        }
        BAR();
    }

    // epilogue: h2o for t = 199 (input h1pre(199) in xa[(Tt-1)&1])
    {
        const half8* hx = xa_f[(Tt - 1) & 1];
        floatx4 acc_o = {0,0,0,0};
#pragma unroll
        for (int k = 0; k < 4; k++) acc_o = MFMA16(hx[k*64 + lane], p_o[k], acc_o);
#pragma unroll
        for (int r2 = 0; r2 < 4; r2++) {
            int brow = q*4 + r2;
            float v = ftanh(acc_o[r2] + bo);
            out3[((long)(b0 + brow)*Tt + (Tt - 1))*256 + 128 + col] = v;
        }
    }
}

extern "C" void kernel_launch(void* const* d_in, const int* in_sizes, int n_in,
                              void* d_out, int out_size, void* d_ws, size_t ws_size,
                              hipStream_t stream) {
    const int*   il    = (const int*)  d_in[0];
    const float* msk   = (const float*)d_in[1];
    const int*   negl  = (const int*)  d_in[2];
    const float* emb   = (const float*)d_in[3];
    const float* Wih   = (const float*)d_in[4];
    const float* Whh   = (const float*)d_in[5];
    const float* bih   = (const float*)d_in[6];
    const float* bhh   = (const float*)d_in[7];
    const float* h2o_w = (const float*)d_in[8];
    const float* h2o_b = (const float*)d_in[9];
    float* out = (float*)d_out;
    ushort* wbuf = (ushort*)d_ws;

    pack_weights<<<(WTOT + 255)/256, 256, 0, stream>>>(Wih, Whh, h2o_w, wbuf);
    gru_fused<<<256, 512, 0, stream>>>(il, msk, negl, emb, bih, bhh, h2o_b, wbuf, out);
}